// Round 1
// baseline (183.770 us; speedup 1.0000x reference)
//
#include <hip/hip_runtime.h>

// ProtoSimLoss: fused group-centroid contrastive loss.
// Pipeline: A2(gid+count) -> A3(scan) -> A4(fill CSR) -> B(centroids) ->
//           C(dist sums + cf->bf16) -> D(density/percentile -> scale2) ->
//           E(MFMA GEMM + online (M,E,S) row partials) -> F(merge+loss) -> G(mean)

typedef __bf16 v8bf __attribute__((ext_vector_type(8)));
typedef __bf16 v4bf __attribute__((ext_vector_type(4)));
typedef float  v4f  __attribute__((ext_vector_type(4)));
typedef unsigned int u32x4 __attribute__((ext_vector_type(4)));

#define B_ROWS 16384
#define ROWS   32768
#define NGRP   1024
#define DIM    512
#define LOG2E  1.4426950408889634f
#define LN2    0.6931471805599453f

__device__ __forceinline__ float wredSum(float v){
#pragma unroll
  for (int o = 32; o > 0; o >>= 1) v += __shfl_xor(v, o);
  return v;
}
__device__ __forceinline__ float wredMax(float v){
#pragma unroll
  for (int o = 32; o > 0; o >>= 1) v = fmaxf(v, __shfl_xor(v, o));
  return v;
}

// ---- A2: gid + base counts -------------------------------------------------
__global__ void kA2(const int* __restrict__ subj, const int* __restrict__ lab,
                    int* __restrict__ base_cnt, int* __restrict__ gid_arr){
  int i = blockIdx.x * 256 + threadIdx.x;           // 16384
  int g = subj[i] * 16 + lab[i];
  gid_arr[i] = g;
  atomicAdd(&base_cnt[g], 1);
}

// ---- A3: exclusive scan of base_cnt (single block, 1024 thr) ---------------
__global__ void kA3(const int* __restrict__ base_cnt, int* __restrict__ offs,
                    int* __restrict__ fillp){
  __shared__ int sb[NGRP];
  int t = threadIdx.x;
  int c = base_cnt[t];
  sb[t] = c;
  __syncthreads();
  for (int off = 1; off < NGRP; off <<= 1){
    int v = (t >= off) ? sb[t - off] : 0;
    __syncthreads();
    sb[t] += v;
    __syncthreads();
  }
  int ex = sb[t] - c;
  offs[t] = ex;
  fillp[t] = ex;
}

// ---- A4: fill CSR row list --------------------------------------------------
__global__ void kA4(const int* __restrict__ gid_arr, int* __restrict__ fillp,
                    int* __restrict__ row_list){
  int i = blockIdx.x * 256 + threadIdx.x;           // 16384
  int pos = atomicAdd(&fillp[gid_arr[i]], 1);
  row_list[pos] = i;
}

// ---- B: per-group centroid (fp32 + bf16 copies) -----------------------------
__global__ void kB(const float* __restrict__ X, const int* __restrict__ base_cnt,
                   const int* __restrict__ offs, const int* __restrict__ row_list,
                   float* __restrict__ cent_f, __bf16* __restrict__ cent_b){
  int g = blockIdx.x, t = threadIdx.x;              // 1024 blocks x 128 thr
  int n = base_cnt[g], off = offs[g];
  float ax = 0.f, ay = 0.f, az = 0.f, aw = 0.f;
  for (int j = 0; j < n; ++j){
    int r = row_list[off + j];
    const float4* p = (const float4*)(X + (size_t)r * 1024);
    float4 a = p[t];        // v = 0
    float4 b = p[t + 128];  // v = 1
    ax += a.x + b.x; ay += a.y + b.y; az += a.z + b.z; aw += a.w + b.w;
  }
  int cnt2 = 2 * n;
  float inv = 1.0f / (float)(cnt2 > 1 ? cnt2 : 1);
  float4 c; c.x = ax * inv; c.y = ay * inv; c.z = az * inv; c.w = aw * inv;
  ((float4*)(cent_f + (size_t)g * DIM))[t] = c;
  v4bf cb; cb[0] = (__bf16)c.x; cb[1] = (__bf16)c.y; cb[2] = (__bf16)c.z; cb[3] = (__bf16)c.w;
  *(v4bf*)(cent_b + (size_t)g * DIM + t * 4) = cb;
}

// ---- C: dist -> sqrt(dist) segment sums; also write cf in bf16 --------------
__global__ void kC(const float* __restrict__ X, const int* __restrict__ subj,
                   const int* __restrict__ lab, const float* __restrict__ cent_f,
                   float* __restrict__ msq, __bf16* __restrict__ cfb){
  int w = threadIdx.x >> 6, lane = threadIdx.x & 63;
  int r = blockIdx.x * 4 + w;                       // 8192 blocks x 4 waves
  int i = r & (B_ROWS - 1), v = r >> 14;
  int g = subj[i] * 16 + lab[i];
  const float4* xr = (const float4*)(X + ((size_t)(i * 2 + v)) * DIM);
  const float4* cr = (const float4*)(cent_f + (size_t)g * DIM);
  float4 x0 = xr[lane], x1 = xr[lane + 64];
  float4 c0 = cr[lane], c1 = cr[lane + 64];
  float s = 0.f, d;
  d = x0.x - c0.x; s += d * d;  d = x0.y - c0.y; s += d * d;
  d = x0.z - c0.z; s += d * d;  d = x0.w - c0.w; s += d * d;
  d = x1.x - c1.x; s += d * d;  d = x1.y - c1.y; s += d * d;
  d = x1.z - c1.z; s += d * d;  d = x1.w - c1.w; s += d * d;
  // store cf bf16
  v4bf b0; b0[0]=(__bf16)x0.x; b0[1]=(__bf16)x0.y; b0[2]=(__bf16)x0.z; b0[3]=(__bf16)x0.w;
  v4bf b1; b1[0]=(__bf16)x1.x; b1[1]=(__bf16)x1.y; b1[2]=(__bf16)x1.z; b1[3]=(__bf16)x1.w;
  *(v4bf*)(cfb + (size_t)r * DIM + lane * 4)       = b0;
  *(v4bf*)(cfb + (size_t)r * DIM + 256 + lane * 4) = b1;
  s = wredSum(s);
  if (lane == 0){
    float dist = sqrtf(s);
    atomicAdd(&msq[g], sqrtf(dist));
  }
}

// ---- D: density, percentile clip, scale2 = log2e/density --------------------
__global__ void kD(const int* __restrict__ base_cnt, const float* __restrict__ msq,
                   float* __restrict__ scale2){
  __shared__ float sd[NGRP];
  __shared__ float ss[NGRP];
  __shared__ float rb[16];
  int t = threadIdx.x;                               // 1024 threads
  int lane = t & 63, wid = t >> 6;
  int cnt2 = 2 * base_cnt[t];
  float safe = (float)(cnt2 > 1 ? cnt2 : 1);
  float v = (msq[t] / safe) / logf((float)cnt2 + 10.0f);
  float d1 = (cnt2 > 1) ? v : 0.0f;
  float wm = wredMax(d1);
  if (lane == 0) rb[wid] = wm;
  __syncthreads();
  float x = (lane < 16) ? rb[lane] : -3.0e38f;
  if (wid == 0){ x = wredMax(x); if (lane == 0) rb[0] = x; }
  __syncthreads();
  float dmax = rb[0];
  float d2 = (cnt2 > 1) ? d1 : dmax;
  sd[t] = d2;
  __syncthreads();
  int rank = 0;
  for (int j = 0; j < NGRP; ++j){
    float dj = sd[j];
    rank += (dj < d2) || (dj == d2 && j < t);
  }
  ss[rank] = d2;
  __syncthreads();
  float p10 = ss[102] + 0.3f * (ss[103] - ss[102]);  // (1023*0.1)=102.3
  float p90 = ss[920] + 0.7f * (ss[921] - ss[920]);  // (1023*0.9)=920.7
  float c = fminf(fmaxf(d2, p10), p90);
  __syncthreads();
  float wsm = wredSum(c);
  if (lane == 0) rb[wid] = wsm;
  __syncthreads();
  float y = (lane < 16) ? rb[lane] : 0.0f;
  if (wid == 0){ y = wredSum(y); if (lane == 0) rb[0] = y; }
  __syncthreads();
  float mean = rb[0] * (1.0f / 1024.0f);
  scale2[t] = LOG2E * mean / (0.1f * c);
}

// ---- E: 128x128 MFMA GEMM, fused per-row (M,E,S) partial epilogue -----------
__global__ __launch_bounds__(256)
void kE(const __bf16* __restrict__ cfb, const __bf16* __restrict__ centb,
        const float* __restrict__ scale2, const int* __restrict__ gid_arr,
        float* __restrict__ pm, float* __restrict__ pe, float* __restrict__ ps){
  __shared__ u32x4 smA[1024];   // [128 rows][8 x 16B], XOR-swizzled
  __shared__ u32x4 smB[1024];
  int tid = threadIdx.x, lane = tid & 63, w = tid >> 6;
  int wr = w >> 1, wc = w & 1;
  int l15 = lane & 15, lhi = lane >> 4;
  int bid = blockIdx.x;
  int nb = bid & 7, mb = bid >> 3;

  const u32x4* gA = (const u32x4*)cfb;    // cf row = 64 u32x4
  const u32x4* gB = (const u32x4*)centb;  // centroid row = 64 u32x4

  int srow = tid >> 1, shalf = tid & 1;
  int swz = srow & 7;
  int arow = (mb * 128 + srow) * 64;
  int brow = (nb * 128 + srow) * 64;
  int lbase = srow * 8;

  v4f acc[4][4];
#pragma unroll
  for (int a1 = 0; a1 < 4; ++a1)
#pragma unroll
    for (int a2 = 0; a2 < 4; ++a2)
      acc[a1][a2] = (v4f){0.f, 0.f, 0.f, 0.f};

  u32x4 av[4], bv[4];
  auto stage_load = [&](int ksv){
    int kb = ksv * 8;
#pragma unroll
    for (int j = 0; j < 4; ++j){
      int idx16 = shalf * 4 + j;
      av[j] = gA[arow + kb + idx16];
      bv[j] = gB[brow + kb + idx16];
    }
  };

  stage_load(0);
  for (int ks = 0; ks < 8; ++ks){
    __syncthreads();            // previous compute's LDS reads done
#pragma unroll
    for (int j = 0; j < 4; ++j){
      int idx16 = shalf * 4 + j;
      smA[lbase + (idx16 ^ swz)] = av[j];
      smB[lbase + (idx16 ^ swz)] = bv[j];
    }
    __syncthreads();
    if (ks < 7) stage_load(ks + 1);   // prefetch next tile across compute
#pragma unroll
    for (int kk = 0; kk < 2; ++kk){
      v8bf a[4], b[4];
#pragma unroll
      for (int f = 0; f < 4; ++f){
        int rA = wr * 64 + f * 16 + l15;
        a[f] = __builtin_bit_cast(v8bf, smA[rA * 8 + ((kk * 4 + lhi) ^ (rA & 7))]);
        int rB = wc * 64 + f * 16 + l15;
        b[f] = __builtin_bit_cast(v8bf, smB[rB * 8 + ((kk * 4 + lhi) ^ (rB & 7))]);
      }
#pragma unroll
      for (int fm = 0; fm < 4; ++fm)
#pragma unroll
        for (int fn = 0; fn < 4; ++fn)
          acc[fm][fn] = __builtin_amdgcn_mfma_f32_16x16x32_bf16(a[fm], b[fn], acc[fm][fn], 0, 0, 0);
    }
  }

  // Epilogue: per-row (M2, E, S2) over this block's 128 columns (exp2 domain)
  int colbase = nb * 128 + wc * 64;
  float sc[4];
#pragma unroll
  for (int fn = 0; fn < 4; ++fn) sc[fn] = scale2[colbase + fn * 16 + l15];
  int gsb = colbase >> 4;                 // group-subject base, +fn
  int slot = nb * 2 + wc;

#pragma unroll
  for (int fm = 0; fm < 4; ++fm){
    int rbase = mb * 128 + wr * 64 + fm * 16 + lhi * 4;
#pragma unroll
    for (int j = 0; j < 4; ++j){
      int row = rbase + j;
      int gr = gid_arr[row & (B_ROWS - 1)];
      float labeq = ((gr & 15) == l15) ? 1.0f : 0.0f;
      int rsub = gr >> 4;
      float vv[4];
      float m2 = -3.0e38f;
#pragma unroll
      for (int fn = 0; fn < 4; ++fn){
        vv[fn] = acc[fm][fn][j] * sc[fn];
        m2 = fmaxf(m2, vv[fn]);
      }
      float e = 0.f, s = 0.f;
#pragma unroll
      for (int fn = 0; fn < 4; ++fn){
        float mk = (rsub != (gsb + fn)) ? labeq : 0.0f;
        e += mk * exp2f(vv[fn] - m2);
        s += mk * vv[fn];
      }
      // butterfly-merge across the 16 lanes holding the same 4 rows
#pragma unroll
      for (int off = 1; off < 16; off <<= 1){
        float mo = __shfl_xor(m2, off);
        float eo = __shfl_xor(e, off);
        float so = __shfl_xor(s, off);
        float mn = fmaxf(m2, mo);
        e = e * exp2f(m2 - mn) + eo * exp2f(mo - mn);
        s += so;
        m2 = mn;
      }
      if (l15 == 0){
        pm[slot * ROWS + row] = m2;
        pe[slot * ROWS + row] = e;
        ps[slot * ROWS + row] = s;
      }
    }
  }
}

// ---- F: merge 16 partials/row, loss per row, block-sum -----------------------
__global__ void kF(const float* __restrict__ pm, const float* __restrict__ pe,
                   const float* __restrict__ ps, float* __restrict__ loss_sum){
  int r = blockIdx.x * 256 + threadIdx.x;           // 32768
  float M = -3.0e38f, E = 0.f, S = 0.f;
#pragma unroll
  for (int p = 0; p < 16; ++p){
    float m = pm[p * ROWS + r];
    float e = pe[p * ROWS + r];
    float s = ps[p * ROWS + r];
    float mn = fmaxf(M, m);
    E = E * exp2f(M - mn) + e * exp2f(m - mn);
    S += s;
    M = mn;
  }
  // loss = ln(961 + E) + ln2*M - ln2*S/63
  float loss = logf(961.0f + E) + LN2 * M - LN2 * (S * (1.0f / 63.0f));
  __shared__ float sb[4];
  float wsum = wredSum(loss);
  int lane = threadIdx.x & 63, wid = threadIdx.x >> 6;
  if (lane == 0) sb[wid] = wsum;
  __syncthreads();
  if (threadIdx.x == 0) atomicAdd(loss_sum, sb[0] + sb[1] + sb[2] + sb[3]);
}

// ---- G: final mean ------------------------------------------------------------
__global__ void kG(const float* __restrict__ loss_sum, float* __restrict__ out){
  out[0] = loss_sum[0] * (1.0f / (float)ROWS);
}

extern "C" void kernel_launch(void* const* d_in, const int* in_sizes, int n_in,
                              void* d_out, int out_size, void* d_ws, size_t ws_size,
                              hipStream_t stream){
  const float* X   = (const float*)d_in[0];
  const int* subj  = (const int*)d_in[1];
  const int* lab   = (const int*)d_in[2];
  float* out = (float*)d_out;
  char* ws = (char*)d_ws;

  // workspace layout (bytes)
  int*    base_cnt = (int*)(ws + 0);                 // 4096
  float*  msq      = (float*)(ws + 4096);            // 4096
  float*  loss_s   = (float*)(ws + 8192);            // 16 (pad 256)
  int*    offs     = (int*)(ws + 8448);              // 4096
  int*    fillp    = (int*)(ws + 12544);             // 4096
  int*    gid_arr  = (int*)(ws + 16640);             // 65536
  int*    row_list = (int*)(ws + 82176);             // 65536
  float*  scale2   = (float*)(ws + 147712);          // 4096
  float*  cent_f   = (float*)(ws + 151808);          // 2 MB
  __bf16* cent_b   = (__bf16*)(ws + 2248960);        // 1 MB
  __bf16* cfb      = (__bf16*)(ws + 3297536);        // 32 MB
  float*  pm       = (float*)(ws + 36851968);        // 2 MB
  float*  pe       = (float*)(ws + 38949120);        // 2 MB
  float*  ps       = (float*)(ws + 41046272);        // 2 MB  (end: 43143424)

  hipMemsetAsync(ws, 0, 8208, stream);               // base_cnt, msq, loss_s

  kA2<<<64, 256, 0, stream>>>(subj, lab, base_cnt, gid_arr);
  kA3<<<1, 1024, 0, stream>>>(base_cnt, offs, fillp);
  kA4<<<64, 256, 0, stream>>>(gid_arr, fillp, row_list);
  kB <<<1024, 128, 0, stream>>>(X, base_cnt, offs, row_list, cent_f, cent_b);
  kC <<<8192, 256, 0, stream>>>(X, subj, lab, cent_f, msq, cfb);
  kD <<<1, 1024, 0, stream>>>(base_cnt, msq, scale2);
  kE <<<2048, 256, 0, stream>>>(cfb, cent_b, scale2, gid_arr, pm, pe, ps);
  kF <<<128, 256, 0, stream>>>(pm, pe, ps, loss_s);
  kG <<<1, 1, 0, stream>>>(loss_s, out);
}

// Round 2
// 166.818 us; speedup vs baseline: 1.1016x; 1.1016x over previous
//
#include <hip/hip_runtime.h>

// ProtoSimLoss: fused group-centroid contrastive loss.
// A2(gid+count) -> A3(scan) -> A4(fill CSR) -> B(centroids) ->
// C(dist sums + cf->bf16) -> D(density/percentile -> scale2) ->
// E(swapped-orientation MFMA GEMM, fully fused online (M,E,S) + loss) -> G(mean)

typedef __bf16 v8bf __attribute__((ext_vector_type(8)));
typedef __bf16 v4bf __attribute__((ext_vector_type(4)));
typedef float  v4f  __attribute__((ext_vector_type(4)));
typedef unsigned int u32x4 __attribute__((ext_vector_type(4)));

#define B_ROWS 16384
#define ROWS   32768
#define NGRP   1024
#define DIM    512
#define LOG2E  1.4426950408889634f
#define LN2    0.6931471805599453f

__device__ __forceinline__ float wredSum(float v){
#pragma unroll
  for (int o = 32; o > 0; o >>= 1) v += __shfl_xor(v, o);
  return v;
}
__device__ __forceinline__ float wredMax(float v){
#pragma unroll
  for (int o = 32; o > 0; o >>= 1) v = fmaxf(v, __shfl_xor(v, o));
  return v;
}

// ---- A2: gid + base counts -------------------------------------------------
__global__ void kA2(const int* __restrict__ subj, const int* __restrict__ lab,
                    int* __restrict__ base_cnt, int* __restrict__ gid_arr){
  int i = blockIdx.x * 256 + threadIdx.x;           // 16384
  int g = subj[i] * 16 + lab[i];
  gid_arr[i] = g;
  atomicAdd(&base_cnt[g], 1);
}

// ---- A3: exclusive scan of base_cnt (single block, 1024 thr) ---------------
__global__ void kA3(const int* __restrict__ base_cnt, int* __restrict__ offs,
                    int* __restrict__ fillp){
  __shared__ int sb[NGRP];
  int t = threadIdx.x;
  int c = base_cnt[t];
  sb[t] = c;
  __syncthreads();
  for (int off = 1; off < NGRP; off <<= 1){
    int v = (t >= off) ? sb[t - off] : 0;
    __syncthreads();
    sb[t] += v;
    __syncthreads();
  }
  int ex = sb[t] - c;
  offs[t] = ex;
  fillp[t] = ex;
}

// ---- A4: fill CSR row list --------------------------------------------------
__global__ void kA4(const int* __restrict__ gid_arr, int* __restrict__ fillp,
                    int* __restrict__ row_list){
  int i = blockIdx.x * 256 + threadIdx.x;           // 16384
  int pos = atomicAdd(&fillp[gid_arr[i]], 1);
  row_list[pos] = i;
}

// ---- B: per-group centroid (fp32 + bf16 copies) -----------------------------
__global__ void kB(const float* __restrict__ X, const int* __restrict__ base_cnt,
                   const int* __restrict__ offs, const int* __restrict__ row_list,
                   float* __restrict__ cent_f, __bf16* __restrict__ cent_b){
  int g = blockIdx.x, t = threadIdx.x;              // 1024 blocks x 128 thr
  int n = base_cnt[g], off = offs[g];
  float ax = 0.f, ay = 0.f, az = 0.f, aw = 0.f;
  for (int j = 0; j < n; ++j){
    int r = row_list[off + j];
    const float4* p = (const float4*)(X + (size_t)r * 1024);
    float4 a = p[t];        // v = 0
    float4 b = p[t + 128];  // v = 1
    ax += a.x + b.x; ay += a.y + b.y; az += a.z + b.z; aw += a.w + b.w;
  }
  int cnt2 = 2 * n;
  float inv = 1.0f / (float)(cnt2 > 1 ? cnt2 : 1);
  float4 c; c.x = ax * inv; c.y = ay * inv; c.z = az * inv; c.w = aw * inv;
  ((float4*)(cent_f + (size_t)g * DIM))[t] = c;
  v4bf cb; cb[0] = (__bf16)c.x; cb[1] = (__bf16)c.y; cb[2] = (__bf16)c.z; cb[3] = (__bf16)c.w;
  *(v4bf*)(cent_b + (size_t)g * DIM + t * 4) = cb;
}

// ---- C: dist -> sqrt(dist) segment sums; also write cf in bf16 --------------
__global__ void kC(const float* __restrict__ X, const int* __restrict__ subj,
                   const int* __restrict__ lab, const float* __restrict__ cent_f,
                   float* __restrict__ msq, __bf16* __restrict__ cfb){
  int w = threadIdx.x >> 6, lane = threadIdx.x & 63;
  int r = blockIdx.x * 4 + w;                       // 8192 blocks x 4 waves
  int i = r & (B_ROWS - 1), v = r >> 14;
  int g = subj[i] * 16 + lab[i];
  const float4* xr = (const float4*)(X + ((size_t)(i * 2 + v)) * DIM);
  const float4* cr = (const float4*)(cent_f + (size_t)g * DIM);
  float4 x0 = xr[lane], x1 = xr[lane + 64];
  float4 c0 = cr[lane], c1 = cr[lane + 64];
  float s = 0.f, d;
  d = x0.x - c0.x; s += d * d;  d = x0.y - c0.y; s += d * d;
  d = x0.z - c0.z; s += d * d;  d = x0.w - c0.w; s += d * d;
  d = x1.x - c1.x; s += d * d;  d = x1.y - c1.y; s += d * d;
  d = x1.z - c1.z; s += d * d;  d = x1.w - c1.w; s += d * d;
  v4bf b0; b0[0]=(__bf16)x0.x; b0[1]=(__bf16)x0.y; b0[2]=(__bf16)x0.z; b0[3]=(__bf16)x0.w;
  v4bf b1; b1[0]=(__bf16)x1.x; b1[1]=(__bf16)x1.y; b1[2]=(__bf16)x1.z; b1[3]=(__bf16)x1.w;
  *(v4bf*)(cfb + (size_t)r * DIM + lane * 4)       = b0;
  *(v4bf*)(cfb + (size_t)r * DIM + 256 + lane * 4) = b1;
  s = wredSum(s);
  if (lane == 0){
    float dist = sqrtf(s);
    atomicAdd(&msq[g], sqrtf(dist));
  }
}

// ---- D: density, percentile clip, scale2 = log2e/density --------------------
__global__ void kD(const int* __restrict__ base_cnt, const float* __restrict__ msq,
                   float* __restrict__ scale2){
  __shared__ float sd[NGRP];
  __shared__ float ss[NGRP];
  __shared__ float rb[16];
  int t = threadIdx.x;                               // 1024 threads
  int lane = t & 63, wid = t >> 6;
  int cnt2 = 2 * base_cnt[t];
  float safe = (float)(cnt2 > 1 ? cnt2 : 1);
  float v = (msq[t] / safe) / logf((float)cnt2 + 10.0f);
  float d1 = (cnt2 > 1) ? v : 0.0f;
  float wm = wredMax(d1);
  if (lane == 0) rb[wid] = wm;
  __syncthreads();
  float x = (lane < 16) ? rb[lane] : -3.0e38f;
  if (wid == 0){ x = wredMax(x); if (lane == 0) rb[0] = x; }
  __syncthreads();
  float dmax = rb[0];
  float d2 = (cnt2 > 1) ? d1 : dmax;
  sd[t] = d2;
  __syncthreads();
  int rank = 0;
  for (int j = 0; j < NGRP; ++j){
    float dj = sd[j];
    rank += (dj < d2) || (dj == d2 && j < t);
  }
  ss[rank] = d2;
  __syncthreads();
  float p10 = ss[102] + 0.3f * (ss[103] - ss[102]);
  float p90 = ss[920] + 0.7f * (ss[921] - ss[920]);
  float c = fminf(fmaxf(d2, p10), p90);
  __syncthreads();
  float wsm = wredSum(c);
  if (lane == 0) rb[wid] = wsm;
  __syncthreads();
  float y = (lane < 16) ? rb[lane] : 0.0f;
  if (wid == 0){ y = wredSum(y); if (lane == 0) rb[0] = y; }
  __syncthreads();
  float mean = rb[0] * (1.0f / 1024.0f);
  scale2[t] = LOG2E * mean / (0.1f * c);
}

// ---- E: swapped GEMM (sim^T = cent x cf^T) + fully fused online loss --------
// Block: 256 thr (4 waves), 64 cf rows (16/wave, 1/lane). cf rows live in
// VGPRs (16 u32x4 per lane, lane's lhi K-slice). Loop over 8 group-tiles of
// 128; per tile, K-loop streams cent [128x64] through double-buffered LDS
// ([128][9] u32x4, +1 pad => conflict-free). Accumulator layout puts groups
// in (lhi*4+j): per-gb fold is in-register; final 2-step lhi butterfly.
__global__ __launch_bounds__(256, 2)
void kE(const __bf16* __restrict__ cfb, const __bf16* __restrict__ centb,
        const float* __restrict__ scale2, const int* __restrict__ gid_arr,
        float* __restrict__ loss_sum){
  __shared__ u32x4 cent[2][128 * 9];
  __shared__ float sscale[NGRP];
  __shared__ float red[4];
  int tid = threadIdx.x, lane = tid & 63, w = tid >> 6;
  int l15 = lane & 15, lhi = lane >> 4;
  int row = blockIdx.x * 64 + w * 16 + l15;          // global cf row (N dim)

  const u32x4* gA = (const u32x4*)centb;             // cent row = 64 u32x4
  const u32x4* gB = (const u32x4*)cfb;               // cf row   = 64 u32x4

  // preload scale2 into LDS (1024 floats)
  ((v4f*)sscale)[tid] = ((const v4f*)scale2)[tid];

  // cf row -> registers: 16 chunks of 16B (this lane's lhi K-slice)
  u32x4 breg[16];
  {
    const u32x4* rp = gB + (size_t)row * 64 + lhi;
#pragma unroll
    for (int c = 0; c < 16; ++c) breg[c] = rp[c * 4];
  }

  int g = gid_arr[row & (B_ROWS - 1)];
  int rsub = g >> 4, rlab = g & 15;
  float labeq[4];
#pragma unroll
  for (int j = 0; j < 4; ++j) labeq[j] = (rlab == lhi * 4 + j) ? 1.0f : 0.0f;

  u32x4 st[4];
  auto stage = [&](int tt){
    int gb = tt >> 3, ks = tt & 7;
#pragma unroll
    for (int c2 = 0; c2 < 4; ++c2){
      int flat = c2 * 256 + tid;
      int mrow = flat >> 3, kidx = flat & 7;
      st[c2] = gA[(size_t)(gb * 128 + mrow) * 64 + ks * 8 + kidx];
    }
  };
  auto commit = [&](int buf){
#pragma unroll
    for (int c2 = 0; c2 < 4; ++c2){
      int flat = c2 * 256 + tid;
      int mrow = flat >> 3, kidx = flat & 7;
      cent[buf][mrow * 9 + kidx] = st[c2];
    }
  };

  v4f acc[8];
#pragma unroll
  for (int fm = 0; fm < 8; ++fm) acc[fm] = (v4f){0.f, 0.f, 0.f, 0.f};
  float M = -3.0e38f, E = 0.f, S = 0.f;

  stage(0); commit(0);
  __syncthreads();

  for (int gb = 0; gb < 8; ++gb){
#pragma unroll
    for (int ks = 0; ks < 8; ++ks){
      int tt = gb * 8 + ks;
      if (tt < 63) stage(tt + 1);                    // issue next-tile loads early
#pragma unroll
      for (int kk = 0; kk < 2; ++kk){
        v8bf afr[8];
#pragma unroll
        for (int fm = 0; fm < 8; ++fm){
          int mrow = fm * 16 + l15;
          afr[fm] = __builtin_bit_cast(v8bf, cent[ks & 1][mrow * 9 + kk * 4 + lhi]);
        }
#pragma unroll
        for (int fm = 0; fm < 8; ++fm)
          acc[fm] = __builtin_amdgcn_mfma_f32_16x16x32_bf16(
              afr[fm], __builtin_bit_cast(v8bf, breg[ks * 2 + kk]), acc[fm], 0, 0, 0);
      }
      if (tt < 63){
        commit((tt + 1) & 1);                        // write-late (T14)
        __syncthreads();
      }
    }
    // ---- fold gb's 32 group-sims into running (M,E,S), all in-register ----
    {
      v4f vs[8];
      float mloc = -3.0e38f;
#pragma unroll
      for (int fm = 0; fm < 8; ++fm){
        v4f sc = *(const v4f*)&sscale[gb * 128 + fm * 16 + lhi * 4];
        v4f t;
#pragma unroll
        for (int j = 0; j < 4; ++j){
          t[j] = acc[fm][j] * sc[j];
          mloc = fmaxf(mloc, t[j]);
        }
        vs[fm] = t;
      }
      float Mn = fmaxf(M, mloc);
      float eadd = 0.f, sadd = 0.f;
#pragma unroll
      for (int fm = 0; fm < 8; ++fm){
        float subne = (rsub != gb * 8 + fm) ? 1.0f : 0.0f;
#pragma unroll
        for (int j = 0; j < 4; ++j){
          float mk = subne * labeq[j];
          eadd += mk * exp2f(vs[fm][j] - Mn);
          sadd += mk * vs[fm][j];
        }
      }
      E = E * exp2f(M - Mn) + eadd;
      S += sadd;
      M = Mn;
#pragma unroll
      for (int fm = 0; fm < 8; ++fm) acc[fm] = (v4f){0.f, 0.f, 0.f, 0.f};
    }
  }

  // merge (M,E,S) across the 4 lhi lanes holding the same cf row
#pragma unroll
  for (int off = 16; off < 64; off <<= 1){
    float mo = __shfl_xor(M, off);
    float eo = __shfl_xor(E, off);
    float so = __shfl_xor(S, off);
    float mn = fmaxf(M, mo);
    E = E * exp2f(M - mn) + eo * exp2f(mo - mn);
    S += so;
    M = mn;
  }
  float loss = logf(961.0f + E) + LN2 * M - LN2 * (S * (1.0f / 63.0f));
  float wsum = wredSum(loss) * 0.25f;                // each row replicated 4x
  if (lane == 0) red[w] = wsum;
  __syncthreads();
  if (tid == 0) atomicAdd(loss_sum, red[0] + red[1] + red[2] + red[3]);
}

// ---- G: final mean ------------------------------------------------------------
__global__ void kG(const float* __restrict__ loss_sum, float* __restrict__ out){
  out[0] = loss_sum[0] * (1.0f / (float)ROWS);
}

extern "C" void kernel_launch(void* const* d_in, const int* in_sizes, int n_in,
                              void* d_out, int out_size, void* d_ws, size_t ws_size,
                              hipStream_t stream){
  const float* X   = (const float*)d_in[0];
  const int* subj  = (const int*)d_in[1];
  const int* lab   = (const int*)d_in[2];
  float* out = (float*)d_out;
  char* ws = (char*)d_ws;

  int*    base_cnt = (int*)(ws + 0);                 // 4096
  float*  msq      = (float*)(ws + 4096);            // 4096
  float*  loss_s   = (float*)(ws + 8192);            // 16 (pad 256)
  int*    offs     = (int*)(ws + 8448);              // 4096
  int*    fillp    = (int*)(ws + 12544);             // 4096
  int*    gid_arr  = (int*)(ws + 16640);             // 65536
  int*    row_list = (int*)(ws + 82176);             // 65536
  float*  scale2   = (float*)(ws + 147712);          // 4096
  float*  cent_f   = (float*)(ws + 151808);          // 2 MB
  __bf16* cent_b   = (__bf16*)(ws + 2248960);        // 1 MB
  __bf16* cfb      = (__bf16*)(ws + 3297536);        // 32 MB (end: 36851968)

  hipMemsetAsync(ws, 0, 8208, stream);               // base_cnt, msq, loss_s

  kA2<<<64, 256, 0, stream>>>(subj, lab, base_cnt, gid_arr);
  kA3<<<1, 1024, 0, stream>>>(base_cnt, offs, fillp);
  kA4<<<64, 256, 0, stream>>>(gid_arr, fillp, row_list);
  kB <<<1024, 128, 0, stream>>>(X, base_cnt, offs, row_list, cent_f, cent_b);
  kC <<<8192, 256, 0, stream>>>(X, subj, lab, cent_f, msq, cfb);
  kD <<<1, 1024, 0, stream>>>(base_cnt, msq, scale2);
  kE <<<512, 256, 0, stream>>>(cfb, cent_b, scale2, gid_arr, loss_s);
  kG <<<1, 1, 0, stream>>>(loss_s, out);
}